// Round 9
// baseline (10581.702 us; speedup 1.0000x reference)
//
#include <hip/hip_runtime.h>
#include <hip/hip_bf16.h>

// LSTM: T=512, B=64, D_IN=512, D_LAT=1024.
// Phase 1: xg = x @ Wx^T + b (bf16 MFMA, pre-permuted bf16 output). Unchanged.
// Phase 2: persistent, 128 WGs x 256 thr (wave = 16 batch rows x 32 gate cols,
//   64 MFMA/step). Wh in VGPRs. SINGLE-HOP sync: h stored as epoch-tagged
//   words (bf16<<16 | tag) via agent-scope 8B atomics; consumers poll the
//   data words themselves (no flags, no vmcnt drains, no barriers in loop).
//   2 parity buffers; tags 1..512; buffers memset to 0 each launch.

typedef __attribute__((ext_vector_type(8))) short short8;
typedef __attribute__((ext_vector_type(4))) short short4v;
typedef __attribute__((ext_vector_type(4))) float f32x4;
typedef unsigned long long ull;

#define T_STEPS 512
#define BATCH   64
#define DIN     512
#define DLAT    1024
#define NWG     128

#define WS_HW   4096                     // 2 x 256KB epoch-word buffers
#define WS_XG   (1u << 20)               // xg at 1 MiB
#define TAGM    0x0000FFFF0000FFFFull

#define MFMA(a, b, c) __builtin_amdgcn_mfma_f32_16x16x32_bf16((a), (b), (c), 0, 0, 0)
#define AT_LD(p)    __hip_atomic_load((p), __ATOMIC_RELAXED, __HIP_MEMORY_SCOPE_AGENT)
#define AT_ST(p, v) __hip_atomic_store((p), (v), __ATOMIC_RELAXED, __HIP_MEMORY_SCOPE_AGENT)

static __device__ __forceinline__ unsigned short f2bf(float f) {
  unsigned u = __builtin_bit_cast(unsigned, f);
  u = (u + 0x7FFFu + ((u >> 16) & 1u)) >> 16;   // RNE
  return (unsigned short)u;
}
static __device__ __forceinline__ float bf2f(unsigned short s) {
  unsigned u = ((unsigned)s) << 16;
  return __builtin_bit_cast(float, u);
}
static __device__ __forceinline__ float sigf(float x) {
  return 1.0f / (1.0f + __expf(-x));
}
static __device__ __forceinline__ float tanhfast(float x) {
  return 2.0f / (1.0f + __expf(-2.0f * x)) - 1.0f;
}
static __device__ __forceinline__ short8 packbf(f32x4 a, f32x4 b) {
  short8 s;
  s[0]=(short)f2bf(a[0]); s[1]=(short)f2bf(a[1]); s[2]=(short)f2bf(a[2]); s[3]=(short)f2bf(a[3]);
  s[4]=(short)f2bf(b[0]); s[5]=(short)f2bf(b[1]); s[6]=(short)f2bf(b[2]); s[7]=(short)f2bf(b[3]);
  return s;
}

// ---------------- Phase 1: xg = x @ Wx^T + bias (unchanged) -----------------
__global__ __launch_bounds__(256, 2) void lstm_phase1(
    const float* __restrict__ x,
    const float* __restrict__ Wf, const float* __restrict__ bfp,
    const float* __restrict__ Wi, const float* __restrict__ bip,
    const float* __restrict__ Wc, const float* __restrict__ bcp,
    const float* __restrict__ Wo, const float* __restrict__ bop,
    unsigned short* __restrict__ xg)
{
  __shared__ __align__(16) short lds[BATCH * DIN];
  const int tid  = threadIdx.x;
  const int nb   = blockIdx.x;    // 0..31
  const int tb4  = blockIdx.y;    // 0..127
  const int lane = tid & 63;
  const int wv   = tid >> 6;
  const int cc   = lane & 15;
  const int q    = lane >> 4;

  const int wg = nb * 4 + wv;     // N-slice 0..127
  const int jj = wg * 8 + (cc & 7);
  short8 bw[2][16];
  #pragma unroll
  for (int T = 0; T < 2; ++T) {
    const float* Wp = (T == 0) ? (cc < 8 ? Wf : Wi) : (cc < 8 ? Wc : Wo);
    const float* base = Wp + (size_t)jj * (DIN + DLAT);
    #pragma unroll
    for (int k = 0; k < 16; ++k) {
      const f32x4* p = (const f32x4*)(base + k * 32 + q * 8);
      bw[T][k] = packbf(p[0], p[1]);
    }
  }
  float biasv[2];
  biasv[0] = (cc < 8 ? bfp : bip)[jj];
  biasv[1] = (cc < 8 ? bcp : bop)[jj];

  for (int tt = 0; tt < 4; ++tt) {
    const int tb = tb4 * 4 + tt;
    const float* xs = x + (size_t)tb * (BATCH * DIN);
    #pragma unroll
    for (int it = 0; it < 16; ++it) {
      int c = tid + 256 * it;
      int row = c >> 6, kc = c & 63;
      const f32x4* p = (const f32x4*)(xs + row * DIN + kc * 8);
      f32x4 v0 = p[0], v1 = p[1];
      int byte = (row * (DIN * 2) + kc * 16) ^ ((row & 7) << 4);
      *(short8*)((char*)lds + byte) = packbf(v0, v1);
    }
    __syncthreads();

    f32x4 acc[4][2] = {};
    #pragma unroll
    for (int k = 0; k < 16; ++k) {
      #pragma unroll
      for (int m = 0; m < 4; ++m) {
        int row = m * 16 + cc;
        int byte = (row * (DIN * 2) + (k * 32 + q * 8) * 2) ^ ((row & 7) << 4);
        short8 a = *(const short8*)((const char*)lds + byte);
        acc[m][0] = MFMA(a, bw[0][k], acc[m][0]);
        acc[m][1] = MFMA(a, bw[1][k], acc[m][1]);
      }
    }
    __syncthreads();

    #pragma unroll
    for (int T = 0; T < 2; ++T) {
      float bias = biasv[T];
      #pragma unroll
      for (int m = 0; m < 4; ++m) {
        f32x4 g = acc[m][T];
        short4v s;
        s[0] = (short)f2bf(g[0] + bias);
        s[1] = (short)f2bf(g[1] + bias);
        s[2] = (short)f2bf(g[2] + bias);
        s[3] = (short)f2bf(g[3] + bias);
        size_t idx = ((((size_t)tb * NWG + wg) * 4 + m) * 2 + T) * 64 + lane;
        *(short4v*)(xg + idx * 4) = s;
      }
    }
  }
}

// ---- batched epoch-word fragment load / check / MFMA (B must be literal) ----
#define LOADB(v, B) do { \
  _Pragma("unroll") \
  for (int j_ = 0; j_ < 4; ++j_) { \
    _Pragma("unroll") \
    for (int u_ = 0; u_ < 4; ++u_) \
      (v)[j_*4+u_] = AT_LD(hr + ((B)*4+j_)*16 + u_); \
  } } while (0)

#define CHECKB(v, okvar) do { ull m_ = 0; \
  _Pragma("unroll") \
  for (int i_ = 0; i_ < 16; ++i_) m_ |= ((v)[i_] & TAGM) ^ tagpair; \
  okvar = (m_ == 0); } while (0)

#define WAITB(v, B) do { bool ok_; CHECKB(v, ok_); int tr_ = 0; \
  while (!__all(ok_)) { if (++tr_ > 32768) break; \
    __builtin_amdgcn_s_sleep(1); LOADB(v, B); CHECKB(v, ok_); } } while (0)

#define MMB(v, B) do { \
  _Pragma("unroll") \
  for (int j_ = 0; j_ < 4; ++j_) { \
    union { unsigned u[4]; short8 s; } a_; \
    _Pragma("unroll") \
    for (int u_ = 0; u_ < 4; ++u_) { \
      unsigned w0_ = (unsigned)(v)[j_*4+u_]; \
      unsigned w1_ = (unsigned)((v)[j_*4+u_] >> 32); \
      a_.u[u_] = __builtin_amdgcn_perm(w1_, w0_, 0x07060302u); } \
    acc0 = MFMA(a_.s, wh[0][(B)*4+j_], acc0); \
    acc1 = MFMA(a_.s, wh[1][(B)*4+j_], acc1); } } while (0)

// ---------------- Phase 2: persistent recurrence ----------------------------
__global__ __launch_bounds__(256, 1) void lstm_phase2(
    const float* __restrict__ Wf, const float* __restrict__ Wi,
    const float* __restrict__ Wc, const float* __restrict__ Wo,
    const unsigned short* __restrict__ xg,
    ull* __restrict__ hw,               // 2 x [64][1024] epoch-tagged u32
    float* __restrict__ out)
{
  __shared__ __align__(16) unsigned lds_t[4][16][8];  // packed (bf16<<16)|tag
  __shared__ __align__(16) float    lds_o[4][16][8];  // f32 h for out

  const int tid  = threadIdx.x;
  const int lane = tid & 63;
  const int wv   = tid >> 6;        // M-tile (batch group) 0..3
  const int wg   = blockIdx.x;      // 0..127
  const int cc   = lane & 15;
  const int q    = lane >> 4;
  const int jj   = wg * 8 + (cc & 7);

  // Wh fragments -> registers (256 VGPR/lane)
  short8 wh[2][32];
  #pragma unroll
  for (int T = 0; T < 2; ++T) {
    const float* Wp = (T == 0) ? (cc < 8 ? Wf : Wi) : (cc < 8 ? Wc : Wo);
    const float* base = Wp + (size_t)jj * (DIN + DLAT) + DIN;
    #pragma unroll
    for (int k = 0; k < 32; ++k) {
      const f32x4* p = (const f32x4*)(base + k * 32 + q * 8);
      wh[T][k] = packbf(p[0], p[1]);
    }
  }

  f32x4 cst = {0.f, 0.f, 0.f, 0.f};
  const unsigned short* xbase = xg + (((size_t)wg * 4 + wv) * 2) * 256 + (size_t)lane * 4;
  const int arow  = wv * 16 + cc;
  const int row16 = lane >> 2;      // producer copy indices
  const int ch    = lane & 3;

  short4v xp0 = *(const short4v*)(xbase);
  short4v xp1 = *(const short4v*)(xbase + 256);

  for (int t = 0; t < T_STEPS; ++t) {
    f32x4 acc0 = {0.f,0.f,0.f,0.f}, acc1 = {0.f,0.f,0.f,0.f};

    if (t > 0) {
      // h_{t-1}: poll epoch-tagged words (tag == t), pipelined 4-frag batches
      const ull tagpair = (ull)(unsigned)t | ((ull)(unsigned)t << 32);
      const ull* hr = hw + (size_t)((t - 1) & 1) * 32768 + (size_t)arow * 512 + q * 4;
      ull v0[16], v1[16];
      LOADB(v0, 0);
      LOADB(v1, 1);
      WAITB(v0, 0); MMB(v0, 0);
      LOADB(v0, 2);
      WAITB(v1, 1); MMB(v1, 1);
      LOADB(v1, 3);
      WAITB(v0, 2); MMB(v0, 2);
      LOADB(v0, 4);
      WAITB(v1, 3); MMB(v1, 3);
      LOADB(v1, 5);
      WAITB(v0, 4); MMB(v0, 4);
      LOADB(v0, 6);
      WAITB(v1, 5); MMB(v1, 5);
      LOADB(v1, 7);
      WAITB(v0, 6); MMB(v0, 6);
      WAITB(v1, 7); MMB(v1, 7);
    }

    // ---- gates
    f32x4 g0, g1;
    #pragma unroll
    for (int r = 0; r < 4; ++r) {
      g0[r] = acc0[r] + bf2f((unsigned short)xp0[r]);
      g1[r] = acc1[r] + bf2f((unsigned short)xp1[r]);
    }
    f32x4 g0x, g1x;
    #pragma unroll
    for (int r = 0; r < 4; ++r) {
      g0x[r] = __shfl_xor(g0[r], 8, 64);
      g1x[r] = __shfl_xor(g1[r], 8, 64);
    }
    const bool lo = (cc < 8);
    float hv[4];
    #pragma unroll
    for (int r = 0; r < 4; ++r) {
      float fpre = lo ? g0[r]  : g0x[r];
      float ipre = lo ? g0x[r] : g0[r];
      float cpre = lo ? g1[r]  : g1x[r];
      float opre = lo ? g1x[r] : g1[r];
      float fg = sigf(fpre), ig = sigf(ipre), cd = tanhfast(cpre), og = sigf(opre);
      float cn = fg * cst[r] + ig * cd;
      cst[r] = cn;
      hv[r] = og * tanhfast(cn);
    }

    // ---- wave-local transpose: packed epoch-word + f32 copies
    {
      const unsigned tagw = (unsigned)(t + 1);
      if (lo) {
        #pragma unroll
        for (int r = 0; r < 4; ++r) {
          lds_t[wv][q * 4 + r][cc] = ((unsigned)f2bf(hv[r]) << 16) | tagw;
          lds_o[wv][q * 4 + r][cc] = hv[r];
        }
      }
    }
    asm volatile("s_waitcnt lgkmcnt(0)" ::: "memory");

    // ---- publish: one 8B atomic h-word store + one 8B plain out store
    {
      ull* hwp = hw + (size_t)(t & 1) * 32768
               + (size_t)(wv * 16 + row16) * 512 + wg * 4 + ch;
      AT_ST(hwp, *(const ull*)&lds_t[wv][row16][ch * 2]);
      *(ull*)(out + (size_t)t * 65536 + (size_t)(wv * 16 + row16) * 1024
              + wg * 8 + ch * 2) = *(const ull*)&lds_o[wv][row16][ch * 2];
    }

    // ---- xg prefetch for t+1 (off critical path)
    {
      int tn = (t + 1 < T_STEPS) ? t + 1 : t;
      const unsigned short* xn = xbase + ((size_t)tn << 18);
      xp0 = *(const short4v*)(xn);
      xp1 = *(const short4v*)(xn + 256);
    }
  }
}

extern "C" void kernel_launch(void* const* d_in, const int* in_sizes, int n_in,
                              void* d_out, int out_size, void* d_ws, size_t ws_size,
                              hipStream_t stream) {
  (void)in_sizes; (void)n_in; (void)out_size; (void)ws_size;
  const float* x   = (const float*)d_in[0];
  const float* Wf  = (const float*)d_in[1];
  const float* bfp = (const float*)d_in[2];
  const float* Wi  = (const float*)d_in[3];
  const float* bip = (const float*)d_in[4];
  const float* Wc  = (const float*)d_in[5];
  const float* bcp = (const float*)d_in[6];
  const float* Wo  = (const float*)d_in[7];
  const float* bop = (const float*)d_in[8];
  float* out = (float*)d_out;

  ull*            hwb = (ull*)((char*)d_ws + WS_HW);
  unsigned short* xg  = (unsigned short*)((char*)d_ws + WS_XG);

  // clear epoch tags (stale tags from a previous replay would false-match)
  hipMemsetAsync(d_ws, 0, WS_HW + 2 * 262144, stream);
  lstm_phase1<<<dim3(32, 128), 256, 0, stream>>>(x, Wf, bfp, Wi, bip, Wc, bcp, Wo, bop, xg);
  lstm_phase2<<<dim3(NWG), 256, 0, stream>>>(Wf, Wi, Wc, Wo, xg, hwb, out);
}